// Round 5
// baseline (206.460 us; speedup 1.0000x reference)
//
#include <hip/hip_runtime.h>

#define B_ 32
#define T_ 4096
#define C_ 256
#define R_ (B_*T_)
#define H1_ 128
#define H2_ 64

#define TB 32   // timestep rows per block in kernel 1

// output layout (floats), concatenated in reference return order
#define PROBS_OFF 0
#define TS_OFF  (R_*4)
#define SEG_OFF (TS_OFF + R_)
#define MI_OFF  (SEG_OFF + R_)
#define MC_OFF  (MI_OFF + R_)

// LDS float layout, 12544 floats = 50.2 KB -> 3 blocks/CU:
//   XS  [32][260] at 0       (X tile; overlaid by W2S after GEMM1)
//   W1S [32][128] at 8320    (linear chunk; overlaid by H1S after GEMM1)
//   W2S [128][64] linear at 0 (8192 f <= 8320, overlays XS)
#define XS_OFF  0
#define XS_P    260
#define W1S_OFF 8320          // linear [32][128]
#define H1S_OFF 8320          // [32][132]
#define H1S_P   132
#define W2S_OFF 0             // linear [128][64]
#define SMEMF   12544

__device__ __forceinline__ void fma4(float4& a, float s, const float4& b) {
  a.x = fmaf(s, b.x, a.x); a.y = fmaf(s, b.y, a.y);
  a.z = fmaf(s, b.z, a.z); a.w = fmaf(s, b.w, a.w);
}

__global__ __launch_bounds__(256, 4) void mlp_conv_kernel(
    const float* __restrict__ X, const float* __restrict__ W1, const float* __restrict__ b1,
    const float* __restrict__ W2, const float* __restrict__ b2,
    const float* __restrict__ W3, const float* __restrict__ b3,
    const float* __restrict__ CW, const float* __restrict__ CB,
    float* __restrict__ out)
{
  __shared__ float sm[SMEMF];
  const int tid  = threadIdx.x;
  const int row0 = blockIdx.x * TB;

  // ---- W1 chunk 0 prefetch (regs) — issued before XS staging barrier ----
  float4 st0 = *(const float4*)&W1[0 * 1024 + tid * 4];
  float4 st1 = *(const float4*)&W1[1 * 1024 + tid * 4];
  float4 st2 = *(const float4*)&W1[2 * 1024 + tid * 4];
  float4 st3 = *(const float4*)&W1[3 * 1024 + tid * 4];

  // ---- stage X tile (32 rows x 256) into padded LDS ----
  #pragma unroll
  for (int i2 = 0; i2 < 8; ++i2) {
    int g = tid + 256 * i2;          // f4 index: 32*64 = 2048 total
    int r = g >> 6, m = g & 63;
    float4 v = *(const float4*)&X[(size_t)(row0 + r) * C_ + m * 4];
    *(float4*)&sm[XS_OFF + r * XS_P + m * 4] = v;
  }
  __syncthreads();

  // ---- conv1d (C->1, k=3, SAME over T) + sigmoid -> transition_scores ----
  // lane mapping: row = w*8 + (l&7), partial p = l>>3 -> 2-way LDS conflicts max
  {
    const int l = tid & 63, w = tid >> 6;
    const int rowi = w * 8 + (l & 7);
    const int p = l >> 3;                        // 0..7
    const int grow = row0 + rowi;
    const int tb = grow & (T_ - 1);              // t within its batch row
    float s = 0.f;
    #pragma unroll
    for (int cc = 0; cc < 8; ++cc) {
      const int c = p * 32 + cc * 4;
      float4 x0 = *(const float4*)&sm[XS_OFF + rowi * XS_P + c];
      float4 xm, xp;
      if (tb == 0)             xm = make_float4(0.f, 0.f, 0.f, 0.f);
      else if (rowi >= 1)      xm = *(const float4*)&sm[XS_OFF + (rowi - 1) * XS_P + c];
      else                     xm = *(const float4*)&X[(size_t)(grow - 1) * C_ + c];
      if (tb == T_ - 1)        xp = make_float4(0.f, 0.f, 0.f, 0.f);
      else if (rowi + 1 < TB)  xp = *(const float4*)&sm[XS_OFF + (rowi + 1) * XS_P + c];
      else                     xp = *(const float4*)&X[(size_t)(grow + 1) * C_ + c];
      // conv_w flat layout: [c][k], k=0->x[t-1], 1->x[t], 2->x[t+1]
      float4 wa = *(const float4*)&CW[c * 3 + 0];
      float4 wb = *(const float4*)&CW[c * 3 + 4];
      float4 wc = *(const float4*)&CW[c * 3 + 8];
      s += xm.x * wa.x + x0.x * wa.y + xp.x * wa.z;
      s += xm.y * wa.w + x0.y * wb.x + xp.y * wb.y;
      s += xm.z * wb.z + x0.z * wb.w + xp.z * wc.x;
      s += xm.w * wc.y + x0.w * wc.z + xp.w * wc.w;
    }
    s += __shfl_xor(s, 8);
    s += __shfl_xor(s, 16);
    s += __shfl_xor(s, 32);
    if (p == 0) out[TS_OFF + grow] = 1.f / (1.f + expf(-(s + CB[0])));
  }

  // ---- GEMM1: (32x256)@(256x128), 4x4 per thread.
  //      A: X tile in LDS (broadcast reads). B: W1 in 32-row chunks,
  //      global->reg->LDS staging with 1-chunk-ahead prefetch.
  //      Last chunk prefetches W2 first half into the same regs. ----
  const int rt = tid >> 5, ct = tid & 31;   // 8 row-groups x 32 col-groups
  const int rb = rt * 4;
  float4 acc0 = make_float4(0.f, 0.f, 0.f, 0.f);
  float4 acc1 = acc0, acc2 = acc0, acc3 = acc0;
  for (int kc = 0; kc < 8; ++kc) {
    // write staged chunk to LDS
    *(float4*)&sm[W1S_OFF + 0 * 1024 + tid * 4] = st0;
    *(float4*)&sm[W1S_OFF + 1 * 1024 + tid * 4] = st1;
    *(float4*)&sm[W1S_OFF + 2 * 1024 + tid * 4] = st2;
    *(float4*)&sm[W1S_OFF + 3 * 1024 + tid * 4] = st3;
    __syncthreads();
    if (kc + 1 < 8) {   // prefetch next W1 chunk; latency hidden under compute
      const float* wp = W1 + (size_t)(kc + 1) * 4096;
      st0 = *(const float4*)&wp[0 * 1024 + tid * 4];
      st1 = *(const float4*)&wp[1 * 1024 + tid * 4];
      st2 = *(const float4*)&wp[2 * 1024 + tid * 4];
      st3 = *(const float4*)&wp[3 * 1024 + tid * 4];
    } else {            // prefetch W2 first half (f4 idx 0..1023)
      st0 = ((const float4*)W2)[tid +   0];
      st1 = ((const float4*)W2)[tid + 256];
      st2 = ((const float4*)W2)[tid + 512];
      st3 = ((const float4*)W2)[tid + 768];
    }
    #pragma unroll
    for (int k4 = 0; k4 < 8; ++k4) {
      const int kb = kc * 32 + k4 * 4;
      float4 a0 = *(const float4*)&sm[XS_OFF + (rb + 0) * XS_P + kb];
      float4 a1 = *(const float4*)&sm[XS_OFF + (rb + 1) * XS_P + kb];
      float4 a2 = *(const float4*)&sm[XS_OFF + (rb + 2) * XS_P + kb];
      float4 a3 = *(const float4*)&sm[XS_OFF + (rb + 3) * XS_P + kb];
      float4 q0 = *(const float4*)&sm[W1S_OFF + (k4 * 4 + 0) * H1_ + ct * 4];
      float4 q1 = *(const float4*)&sm[W1S_OFF + (k4 * 4 + 1) * H1_ + ct * 4];
      float4 q2 = *(const float4*)&sm[W1S_OFF + (k4 * 4 + 2) * H1_ + ct * 4];
      float4 q3 = *(const float4*)&sm[W1S_OFF + (k4 * 4 + 3) * H1_ + ct * 4];
      fma4(acc0, a0.x, q0); fma4(acc0, a0.y, q1); fma4(acc0, a0.z, q2); fma4(acc0, a0.w, q3);
      fma4(acc1, a1.x, q0); fma4(acc1, a1.y, q1); fma4(acc1, a1.z, q2); fma4(acc1, a1.w, q3);
      fma4(acc2, a2.x, q0); fma4(acc2, a2.y, q1); fma4(acc2, a2.z, q2); fma4(acc2, a2.w, q3);
      fma4(acc3, a3.x, q0); fma4(acc3, a3.y, q1); fma4(acc3, a3.z, q2); fma4(acc3, a3.w, q3);
    }
    __syncthreads();   // all reads of this chunk done before next write
  }

  // ---- epilogue staging: W2 second half loads + W3/b3 loads (latency
  //      hidden under H1 writes), H1 bias+relu -> H1s, W2 -> W2S ----
  const int ct2 = tid & 15;
  float4 t4a = ((const float4*)W2)[tid + 1024];
  float4 t4b = ((const float4*)W2)[tid + 1280];
  float4 t4c = ((const float4*)W2)[tid + 1536];
  float4 t4d = ((const float4*)W2)[tid + 1792];
  float4 w30 = ((const float4*)W3)[ct2 * 4 + 0];
  float4 w31 = ((const float4*)W3)[ct2 * 4 + 1];
  float4 w32 = ((const float4*)W3)[ct2 * 4 + 2];
  float4 w33 = ((const float4*)W3)[ct2 * 4 + 3];
  float4 b3v = *(const float4*)&b3[0];
  {
    float4 bb = *(const float4*)&b1[ct * 4];
    float4 h;
    h = acc0; h.x = fmaxf(h.x + bb.x, 0.f); h.y = fmaxf(h.y + bb.y, 0.f);
              h.z = fmaxf(h.z + bb.z, 0.f); h.w = fmaxf(h.w + bb.w, 0.f);
    *(float4*)&sm[H1S_OFF + (rb + 0) * H1S_P + ct * 4] = h;
    h = acc1; h.x = fmaxf(h.x + bb.x, 0.f); h.y = fmaxf(h.y + bb.y, 0.f);
              h.z = fmaxf(h.z + bb.z, 0.f); h.w = fmaxf(h.w + bb.w, 0.f);
    *(float4*)&sm[H1S_OFF + (rb + 1) * H1S_P + ct * 4] = h;
    h = acc2; h.x = fmaxf(h.x + bb.x, 0.f); h.y = fmaxf(h.y + bb.y, 0.f);
              h.z = fmaxf(h.z + bb.z, 0.f); h.w = fmaxf(h.w + bb.w, 0.f);
    *(float4*)&sm[H1S_OFF + (rb + 2) * H1S_P + ct * 4] = h;
    h = acc3; h.x = fmaxf(h.x + bb.x, 0.f); h.y = fmaxf(h.y + bb.y, 0.f);
              h.z = fmaxf(h.z + bb.z, 0.f); h.w = fmaxf(h.w + bb.w, 0.f);
    *(float4*)&sm[H1S_OFF + (rb + 3) * H1S_P + ct * 4] = h;
  }
  // W2 -> LDS (XS region is dead after final GEMM1 barrier)
  *(float4*)&sm[W2S_OFF + (tid +    0) * 4] = st0;
  *(float4*)&sm[W2S_OFF + (tid +  256) * 4] = st1;
  *(float4*)&sm[W2S_OFF + (tid +  512) * 4] = st2;
  *(float4*)&sm[W2S_OFF + (tid +  768) * 4] = st3;
  *(float4*)&sm[W2S_OFF + (tid + 1024) * 4] = t4a;
  *(float4*)&sm[W2S_OFF + (tid + 1280) * 4] = t4b;
  *(float4*)&sm[W2S_OFF + (tid + 1536) * 4] = t4c;
  *(float4*)&sm[W2S_OFF + (tid + 1792) * 4] = t4d;
  __syncthreads();

  // ---- GEMM2: (32x128)@(128x64), 2x4 per thread, both operands LDS.
  //      H2 stays in registers. ----
  const int rt2 = tid >> 4;
  float4 c0 = make_float4(0.f, 0.f, 0.f, 0.f), c1 = c0;
  #pragma unroll 8
  for (int k4 = 0; k4 < 32; ++k4) {
    float4 a0 = *(const float4*)&sm[H1S_OFF + (rt2 * 2 + 0) * H1S_P + k4 * 4];
    float4 a1 = *(const float4*)&sm[H1S_OFF + (rt2 * 2 + 1) * H1S_P + k4 * 4];
    float4 q0 = *(const float4*)&sm[W2S_OFF + (k4 * 4 + 0) * H2_ + ct2 * 4];
    float4 q1 = *(const float4*)&sm[W2S_OFF + (k4 * 4 + 1) * H2_ + ct2 * 4];
    float4 q2 = *(const float4*)&sm[W2S_OFF + (k4 * 4 + 2) * H2_ + ct2 * 4];
    float4 q3 = *(const float4*)&sm[W2S_OFF + (k4 * 4 + 3) * H2_ + ct2 * 4];
    fma4(c0, a0.x, q0); fma4(c0, a0.y, q1); fma4(c0, a0.z, q2); fma4(c0, a0.w, q3);
    fma4(c1, a1.x, q0); fma4(c1, a1.y, q1); fma4(c1, a1.z, q2); fma4(c1, a1.w, q3);
  }
  {
    float4 bb = *(const float4*)&b2[ct2 * 4];
    c0.x = fmaxf(c0.x + bb.x, 0.f); c0.y = fmaxf(c0.y + bb.y, 0.f);
    c0.z = fmaxf(c0.z + bb.z, 0.f); c0.w = fmaxf(c0.w + bb.w, 0.f);
    c1.x = fmaxf(c1.x + bb.x, 0.f); c1.y = fmaxf(c1.y + bb.y, 0.f);
    c1.z = fmaxf(c1.z + bb.z, 0.f); c1.w = fmaxf(c1.w + bb.w, 0.f);
  }

  // ---- GEMM3 (64->4) via per-thread partials + 16-lane butterfly ----
  float4 L0 = make_float4(0.f, 0.f, 0.f, 0.f), L1 = L0;
  fma4(L0, c0.x, w30); fma4(L0, c0.y, w31); fma4(L0, c0.z, w32); fma4(L0, c0.w, w33);
  fma4(L1, c1.x, w30); fma4(L1, c1.y, w31); fma4(L1, c1.z, w32); fma4(L1, c1.w, w33);
  #pragma unroll
  for (int d = 1; d < 16; d <<= 1) {
    L0.x += __shfl_xor(L0.x, d); L0.y += __shfl_xor(L0.y, d);
    L0.z += __shfl_xor(L0.z, d); L0.w += __shfl_xor(L0.w, d);
    L1.x += __shfl_xor(L1.x, d); L1.y += __shfl_xor(L1.y, d);
    L1.z += __shfl_xor(L1.z, d); L1.w += __shfl_xor(L1.w, d);
  }
  // softmax + dom/conf; lane ct2==0 writes row0 of pair, ct2==8 writes row1
  {
    float4 L = (ct2 < 8) ? L0 : L1;
    const int grow = row0 + rt2 * 2 + ((ct2 < 8) ? 0 : 1);
    L.x += b3v.x; L.y += b3v.y; L.z += b3v.z; L.w += b3v.w;
    float mx = fmaxf(fmaxf(L.x, L.y), fmaxf(L.z, L.w));
    float e0 = expf(L.x - mx), e1 = expf(L.y - mx), e2 = expf(L.z - mx), e3 = expf(L.w - mx);
    float inv = 1.f / ((e0 + e1) + (e2 + e3));
    float p0 = e0 * inv, p1 = e1 * inv, p2 = e2 * inv, p3 = e3 * inv;
    if ((ct2 & 7) == 0) {
      *(float4*)&out[PROBS_OFF + (size_t)grow * 4] = make_float4(p0, p1, p2, p3);
      int dom = 0; float pm = p0;
      if (p1 > pm) { pm = p1; dom = 1; }
      if (p2 > pm) { pm = p2; dom = 2; }
      if (p3 > pm) { pm = p3; dom = 3; }
      out[MI_OFF + grow] = (float)dom;   // park dom for kernel 2
      out[MC_OFF + grow] = pm;           // park conf for kernel 2
    }
  }
}

// ---- kernel 2: per-batch-row segmentation + segment means ----
__global__ __launch_bounds__(1024, 1) void seg_kernel(
    const float* __restrict__ inten, float* __restrict__ out)
{
  __shared__ float scnt[T_], ssi[T_], ssc[T_];
  __shared__ int wtot[16], wexcl[16];
  const int tid = threadIdx.x;
  const int lane = tid & 63, wid = tid >> 6;
  const size_t base = (size_t)blockIdx.x * T_;
  const float* tsS = out + TS_OFF;
  float* segO = out + SEG_OFF;
  float* miO  = out + MI_OFF;
  float* mcO  = out + MC_OFF;
  const int t4 = tid * 4;

  float4 dv = *(const float4*)&miO[base + t4];        // dom (as float)
  float4 tv = *(const float4*)&tsS[base + t4];        // transition scores
  float4 iv = *(const float4*)&inten[base + t4];      // intensity
  float4 cv = *(const float4*)&mcO[base + t4];        // confidence
  float pd = (tid == 0) ? 0.f : miO[base + t4 - 1];

  for (int i = tid; i < T_; i += 1024) { scnt[i] = 0.f; ssi[i] = 0.f; ssc[i] = 0.f; }

  int c0 = (t4 == 0) ? 0 : (((dv.x != pd)   || (tv.x > 0.7f)) ? 1 : 0);
  int c1 = ((dv.y != dv.x) || (tv.y > 0.7f)) ? 1 : 0;
  int c2 = ((dv.z != dv.y) || (tv.z > 0.7f)) ? 1 : 0;
  int c3 = ((dv.w != dv.z) || (tv.w > 0.7f)) ? 1 : 0;
  int l0 = c0, l1 = c0 + c1, l2 = l1 + c2, l3 = l2 + c3;
  const int tsum = l3;

  // wave-inclusive scan of per-thread sums
  int v = tsum;
  #pragma unroll
  for (int d = 1; d < 64; d <<= 1) {
    int o = __shfl_up(v, (unsigned)d);
    if (lane >= d) v += o;
  }
  if (lane == 63) wtot[wid] = v;
  __syncthreads();
  if (tid < 16) {
    int x = wtot[tid];
    int xx = x;
    #pragma unroll
    for (int d = 1; d < 16; d <<= 1) {
      int o = __shfl_up(xx, (unsigned)d);
      if (tid >= d) xx += o;
    }
    wexcl[tid] = xx - x;   // exclusive wave offset
  }
  __syncthreads();
  const int texcl = wexcl[wid] + (v - tsum);
  const int s0 = texcl + l0, s1 = texcl + l1, s2 = texcl + l2, s3 = texcl + l3;

  // merged LDS atomics for segment sums
  {
    int cur = s0; float aI = iv.x, aC = cv.x, aN = 1.f;
    if (s1 == cur) { aI += iv.y; aC += cv.y; aN += 1.f; }
    else { atomicAdd(&ssi[cur], aI); atomicAdd(&ssc[cur], aC); atomicAdd(&scnt[cur], aN);
           cur = s1; aI = iv.y; aC = cv.y; aN = 1.f; }
    if (s2 == cur) { aI += iv.z; aC += cv.z; aN += 1.f; }
    else { atomicAdd(&ssi[cur], aI); atomicAdd(&ssc[cur], aC); atomicAdd(&scnt[cur], aN);
           cur = s2; aI = iv.z; aC = cv.z; aN = 1.f; }
    if (s3 == cur) { aI += iv.w; aC += cv.w; aN += 1.f; }
    else { atomicAdd(&ssi[cur], aI); atomicAdd(&ssc[cur], aC); atomicAdd(&scnt[cur], aN);
           cur = s3; aI = iv.w; aC = cv.w; aN = 1.f; }
    atomicAdd(&ssi[cur], aI); atomicAdd(&ssc[cur], aC); atomicAdd(&scnt[cur], aN);
  }
  __syncthreads();

  float n0 = scnt[s0], n1 = scnt[s1], n2 = scnt[s2], n3 = scnt[s3];
  float4 m4, q4, g4;
  m4.x = ssi[s0] / n0; m4.y = ssi[s1] / n1; m4.z = ssi[s2] / n2; m4.w = ssi[s3] / n3;
  q4.x = ssc[s0] / n0; q4.y = ssc[s1] / n1; q4.z = ssc[s2] / n2; q4.w = ssc[s3] / n3;
  g4.x = (float)s0; g4.y = (float)s1; g4.z = (float)s2; g4.w = (float)s3;
  *(float4*)&segO[base + t4] = g4;
  *(float4*)&miO[base + t4]  = m4;
  *(float4*)&mcO[base + t4]  = q4;
}

extern "C" void kernel_launch(void* const* d_in, const int* in_sizes, int n_in,
                              void* d_out, int out_size, void* d_ws, size_t ws_size,
                              hipStream_t stream) {
  (void)in_sizes; (void)n_in; (void)out_size; (void)d_ws; (void)ws_size;
  const float* X   = (const float*)d_in[0];
  const float* INT = (const float*)d_in[1];
  const float* W1  = (const float*)d_in[2];
  const float* B1  = (const float*)d_in[3];
  const float* W2  = (const float*)d_in[4];
  const float* B2  = (const float*)d_in[5];
  const float* W3  = (const float*)d_in[6];
  const float* B3  = (const float*)d_in[7];
  const float* CW  = (const float*)d_in[8];
  const float* CB  = (const float*)d_in[9];
  float* out = (float*)d_out;

  hipLaunchKernelGGL(mlp_conv_kernel, dim3(R_ / TB), dim3(256), 0, stream,
                     X, W1, B1, W2, B2, W3, B3, CW, CB, out);
  hipLaunchKernelGGL(seg_kernel, dim3(B_), dim3(1024), 0, stream, INT, out);
}